// Round 6
// baseline (25.730 us; speedup 1.0000x reference)
//
#include <hip/hip_runtime.h>

#define BB 8
#define SS 4096
#define DD 64
#define NH 8
#define NBKT 64
#define OUT_V_ELEMS (BB*SS*DD)   // 2097152 floats of o, then buckets (BB*NH*SS floats)

// Grid: 512 blocks = b(8) * hq(2) * chunk(32 of 128 tokens). Block: 128 thr = 2 waves.
// Wave wv: tokens t0 + wv*64 + tx*8 .. +7 (tx = lane&7); ty = lane>>3 picks 16 of the
// hash-quad's 128 dirs (hash_local = ty>>1, dir-half = ty&1). Thread tile:
// 8 tokens x 16 dirs = 128 acc. 1024 waves total = 1 wave/SIMD -> latency must be
// hidden by ILP: BOTH q (per fq) and rot (per f) are explicitly double-buffered in
// registers so every ds_read batch is issued one step ahead of its use.
__global__ __launch_bounds__(128, 2) void lsh_hash_kernel(
    const float* __restrict__ qk,
    const float* __restrict__ v,
    const float* __restrict__ rot,
    float* __restrict__ out)
{
    __shared__ float q_s[128 * 64];    // [tok][f], f-chunk swizzle: chunk' = fc ^ ((tok>>3)&7)
    __shared__ float rot_s[64 * 128];  // [f][slot*4], slot(c) = (c&3)*8 + (c>>2)

    const int tid = threadIdx.x;
    const int blk = blockIdx.x;
    const int b   = blk >> 6;          // 0..7
    const int hq  = (blk >> 5) & 1;    // 0..1
    const int ch  = blk & 31;          // 0..31
    const int t0  = ch * 128;

    // ---- fused v -> out[0] copy (output 0 == v exactly; self-mask keeps only t==t slots) ----
    {
        const float4* v4 = (const float4*)v;
        float4*       o4 = (float4*)out;
        const int base = blk * 1024 + tid;
#pragma unroll
        for (int j = 0; j < 8; ++j)
            o4[base + j * 128] = v4[base + j * 128];
    }

    // ---- stage qk tile: 128 tok x 16 f-chunks, swizzled ----
    {
        const float4* qg = (const float4*)qk;
#pragma unroll
        for (int k = 0; k < 16; ++k) {
            const int p   = k * 128 + tid;       // 2048 float4
            const int tok = p >> 4, fc = p & 15;
            const float4 x = qg[(b * SS + t0 + tok) * 16 + fc];
            *(float4*)&q_s[tok * 64 + ((fc ^ ((tok >> 3) & 7)) << 2)] = x;
        }
    }
    // ---- stage rot quad: 64 f x 32 dir-chunks, permuted slots ----
    {
        const float4* rg = (const float4*)rot;
#pragma unroll
        for (int k = 0; k < 16; ++k) {
            const int p = k * 128 + tid;         // 2048 float4
            const int f = p >> 5, c = p & 31;
            const float4 x = rg[f * 64 + hq * 32 + c];
            const int slot = (c & 3) * 8 + (c >> 2);
            *(float4*)&rot_s[f * 128 + slot * 4] = x;
        }
    }
    __syncthreads();

    const int lane = tid & 63;
    const int wv   = tid >> 6;
    const int tx   = lane & 7;
    const int ty   = lane >> 3;
    const int trow = (wv * 64 + tx * 8) * 64;    // float base of first owned token row
    const int rbase = ty * 4;                    // float offset of slot ty within a p-group

    float acc[8][16];
#pragma unroll
    for (int a = 0; a < 8; ++a)
#pragma unroll
        for (int c = 0; c < 16; ++c) acc[a][c] = 0.0f;

    float4 qA[8], qB[8];
    float4 rP[4], rQ[4];

#define LOADQ(dst, fq_)                                                    \
    {                                                                      \
        const int qc = (((fq_) ^ tx) << 2);                                \
        _Pragma("unroll")                                                  \
        for (int a = 0; a < 8; ++a)                                        \
            dst[a] = *(const float4*)&q_s[trow + a * 64 + qc];             \
    }
    // thread ty reads quad dir-chunks ty*4+p (p=0..3) at slot p*8+ty -> float p*32+ty*4
#define LOADR(dst, f_)                                                     \
    {                                                                      \
        const int ff = ((f_) < 64 ? (f_) : 0);                             \
        _Pragma("unroll")                                                  \
        for (int p = 0; p < 4; ++p)                                        \
            dst[p] = *(const float4*)&rot_s[ff * 128 + p * 32 + rbase];    \
    }
#define FMAS(qr, CMP, R)                                                   \
    {                                                                      \
        const float rr[16] = {R[0].x, R[0].y, R[0].z, R[0].w,              \
                              R[1].x, R[1].y, R[1].z, R[1].w,              \
                              R[2].x, R[2].y, R[2].z, R[2].w,              \
                              R[3].x, R[3].y, R[3].z, R[3].w};             \
        _Pragma("unroll")                                                  \
        for (int a = 0; a < 8; ++a) {                                      \
            const float qf = qr[a].CMP;                                    \
            _Pragma("unroll")                                              \
            for (int c = 0; c < 16; ++c)                                   \
                acc[a][c] = fmaf(qf, rr[c], acc[a][c]);                    \
        }                                                                  \
    }

    LOADQ(qA, 0);
    LOADR(rP, 0);
#pragma unroll 1
    for (int fq = 0; fq < 16; fq += 2) {
        const int f0 = fq * 4;
        LOADQ(qB, fq + 1);
        LOADR(rQ, f0 + 1); FMAS(qA, x, rP);
        LOADR(rP, f0 + 2); FMAS(qA, y, rQ);
        LOADR(rQ, f0 + 3); FMAS(qA, z, rP);
        LOADR(rP, f0 + 4); FMAS(qA, w, rQ);
        if (fq + 2 < 16) LOADQ(qA, fq + 2);
        LOADR(rQ, f0 + 5); FMAS(qB, x, rP);
        LOADR(rP, f0 + 6); FMAS(qB, y, rQ);
        LOADR(rQ, f0 + 7); FMAS(qB, z, rP);
        LOADR(rP, f0 + 8); FMAS(qB, w, rQ);   // f0+8==64 on last iter -> clamped, unused
    }

    // ---- argmax over concat([r, -r]) with reference tie-breaks ----
    const int h     = hq * 4 + (ty >> 1);
    const int dbase = (ty & 1) * 16;
    float* bout = out + OUT_V_ELEMS + b * (NH * SS) + h * SS + t0 + wv * 64 + tx * 8;

#pragma unroll
    for (int a = 0; a < 8; ++a) {
        float pv = acc[a][0]; int pi = dbase;
        float nv = -acc[a][0]; int ni = dbase;
#pragma unroll
        for (int c = 1; c < 16; ++c) {
            const float x = acc[a][c];
            if (x  > pv) { pv = x;  pi = dbase + c; }   // strict > = first occurrence
            if (-x > nv) { nv = -x; ni = dbase + c; }
        }
        const float opv = __shfl_xor(pv, 8);
        const int   opi = __shfl_xor(pi, 8);
        const float onv = __shfl_xor(nv, 8);
        const int   oni = __shfl_xor(ni, 8);
        if (opv > pv || (opv == pv && opi < pi)) { pv = opv; pi = opi; }
        if (onv > nv || (onv == nv && oni < ni)) { nv = onv; ni = oni; }
        const int idx = (pv >= nv) ? pi : (ni + 32);    // positive half wins ties
        if ((ty & 1) == 0) bout[a] = (float)(idx + h * NBKT);
    }
#undef LOADQ
#undef LOADR
#undef FMAS
}

extern "C" void kernel_launch(void* const* d_in, const int* in_sizes, int n_in,
                              void* d_out, int out_size, void* d_ws, size_t ws_size,
                              hipStream_t stream) {
    const float* qk  = (const float*)d_in[0];
    const float* v   = (const float*)d_in[1];
    const float* rot = (const float*)d_in[2];
    float* out = (float*)d_out;
    hipLaunchKernelGGL(lsh_hash_kernel, dim3(512), dim3(128), 0, stream,
                       qk, v, rot, out);
}

// Round 7
// 24.587 us; speedup vs baseline: 1.0465x; 1.0465x over previous
//
#include <hip/hip_runtime.h>

#define BB 8
#define SS 4096
#define DD 64
#define NH 8
#define NBKT 64
#define OUT_V_ELEMS (BB*SS*DD)   // 2097152 floats of o, then buckets (BB*NH*SS floats)

// Grid: 512 = b(8) * hq(2) * chunk(32 of 128 tokens). Block: 256 thr = 4 waves.
// Thread tile: 8 tok x 8 dirs (64 acc) -> 2048 waves total = 8 waves/CU = 2/SIMD,
// and 64 KB LDS -> 2 blocks/CU so staging overlaps the other block's compute.
// tx = tid&15 (token group), ty = tid>>4 (8-dir group of the hq-half's 128 dirs).
__global__ __launch_bounds__(256, 2) void lsh_hash_kernel(
    const float* __restrict__ qk,
    const float* __restrict__ v,
    const float* __restrict__ rot,
    float* __restrict__ out)
{
    __shared__ float q_s[128 * 64];    // 32 KB, [tok][f], chunk' = fc ^ ((tok>>3)&7)
    __shared__ float rot_s[64 * 128];  // 32 KB, [f][dir] natural

    const int tid = threadIdx.x;
    const int blk = blockIdx.x;
    const int b   = blk >> 6;          // 0..7
    const int hq  = (blk >> 5) & 1;    // 0..1
    const int ch  = blk & 31;          // 0..31
    const int t0  = ch * 128;

    // ---- fused v -> out[0] copy (output 0 == v exactly; self-mask keeps only t==t slots) ----
    // 524288 float4 = 512 blocks * 1024; 256 threads * 4 each.
    {
        const float4* v4 = (const float4*)v;
        float4*       o4 = (float4*)out;
        const int base = blk * 1024 + tid;
#pragma unroll
        for (int j = 0; j < 4; ++j)
            o4[base + j * 256] = v4[base + j * 256];
    }

    // ---- stage qk tile: 128 tok x 16 f-chunks, swizzled ----
    {
        const float4* qg = (const float4*)qk;
#pragma unroll
        for (int k = 0; k < 8; ++k) {
            const int p   = k * 256 + tid;       // 2048 float4
            const int tok = p >> 4, fc = p & 15;
            const float4 x = qg[(b * SS + t0 + tok) * 16 + fc];
            *(float4*)&q_s[tok * 64 + ((fc ^ ((tok >> 3) & 7)) << 2)] = x;
        }
    }
    // ---- stage rot half: 64 f x 32 dir-chunks, natural layout ----
    {
        const float4* rg = (const float4*)rot;
#pragma unroll
        for (int k = 0; k < 8; ++k) {
            const int p = k * 256 + tid;         // 2048 float4
            const int f = p >> 5, c = p & 31;
            const float4 x = rg[f * 64 + hq * 32 + c];
            *(float4*)&rot_s[f * 128 + c * 4] = x;
        }
    }
    __syncthreads();

    const int tx    = tid & 15;         // token group: toks tx*8 .. +7
    const int ty    = tid >> 4;         // dir group: dirs ty*8 .. +7 of the hq half
    const int trow  = tx * 8 * 64;      // float base of first owned token row
    const int rbase = ty * 8;           // float offset of owned dirs in a rot row

    float acc[8][8];
#pragma unroll
    for (int a = 0; a < 8; ++a)
#pragma unroll
        for (int c = 0; c < 8; ++c) acc[a][c] = 0.0f;

    float4 qA[8], qB[8];
    float4 rP[2], rQ[2];

#define LOADQ(dst, fq_)                                                    \
    {                                                                      \
        const int qc = (((fq_) ^ (tx & 7)) << 2);                          \
        _Pragma("unroll")                                                  \
        for (int a = 0; a < 8; ++a)                                        \
            dst[a] = *(const float4*)&q_s[trow + a * 64 + qc];             \
    }
#define LOADR(dst, f_)                                                     \
    {                                                                      \
        const int ff = ((f_) < 64 ? (f_) : 0);                             \
        dst[0] = *(const float4*)&rot_s[ff * 128 + rbase];                 \
        dst[1] = *(const float4*)&rot_s[ff * 128 + rbase + 4];             \
    }
#define FMAS(qr, CMP, R)                                                   \
    {                                                                      \
        const float rr[8] = {R[0].x, R[0].y, R[0].z, R[0].w,               \
                             R[1].x, R[1].y, R[1].z, R[1].w};              \
        _Pragma("unroll")                                                  \
        for (int a = 0; a < 8; ++a) {                                      \
            const float qf = qr[a].CMP;                                    \
            _Pragma("unroll")                                              \
            for (int c = 0; c < 8; ++c)                                    \
                acc[a][c] = fmaf(qf, rr[c], acc[a][c]);                    \
        }                                                                  \
    }

    LOADQ(qA, 0);
    LOADR(rP, 0);
#pragma unroll 1
    for (int fq = 0; fq < 16; fq += 2) {
        const int f0 = fq * 4;
        LOADQ(qB, fq + 1);
        LOADR(rQ, f0 + 1); FMAS(qA, x, rP);
        LOADR(rP, f0 + 2); FMAS(qA, y, rQ);
        LOADR(rQ, f0 + 3); FMAS(qA, z, rP);
        LOADR(rP, f0 + 4); FMAS(qA, w, rQ);
        if (fq + 2 < 16) LOADQ(qA, fq + 2);
        LOADR(rQ, f0 + 5); FMAS(qB, x, rP);
        LOADR(rP, f0 + 6); FMAS(qB, y, rQ);
        LOADR(rQ, f0 + 7); FMAS(qB, z, rP);
        LOADR(rP, f0 + 8); FMAS(qB, w, rQ);   // clamped on last iter, unused
    }

    // ---- argmax over concat([r, -r]) with reference tie-breaks ----
    const int h     = hq * 4 + (ty >> 2);   // global hash
    const int dbase = (ty & 3) * 8;         // dir offset within the hash
    float* bout = out + OUT_V_ELEMS + b * (NH * SS) + h * SS + t0 + tx * 8;

#pragma unroll
    for (int a = 0; a < 8; ++a) {
        float pv = acc[a][0]; int pi = dbase;
        float nv = -acc[a][0]; int ni = dbase;
#pragma unroll
        for (int c = 1; c < 8; ++c) {
            const float x = acc[a][c];
            if (x  > pv) { pv = x;  pi = dbase + c; }   // strict > = first occurrence
            if (-x > nv) { nv = -x; ni = dbase + c; }
        }
        // merge the 4 lanes (ty&3 = tid bits 4,5 -> lane xor 16, 32) sharing this hash
#pragma unroll
        for (int m = 16; m <= 32; m <<= 1) {
            const float opv = __shfl_xor(pv, m);
            const int   opi = __shfl_xor(pi, m);
            const float onv = __shfl_xor(nv, m);
            const int   oni = __shfl_xor(ni, m);
            if (opv > pv || (opv == pv && opi < pi)) { pv = opv; pi = opi; }
            if (onv > nv || (onv == nv && oni < ni)) { nv = onv; ni = oni; }
        }
        const int idx = (pv >= nv) ? pi : (ni + 32);    // positive half wins ties
        if ((ty & 3) == 0) bout[a] = (float)(idx + h * NBKT);
    }
#undef LOADQ
#undef LOADR
#undef FMAS
}

extern "C" void kernel_launch(void* const* d_in, const int* in_sizes, int n_in,
                              void* d_out, int out_size, void* d_ws, size_t ws_size,
                              hipStream_t stream) {
    const float* qk  = (const float*)d_in[0];
    const float* v   = (const float*)d_in[1];
    const float* rot = (const float*)d_in[2];
    float* out = (float*)d_out;
    hipLaunchKernelGGL(lsh_hash_kernel, dim3(512), dim3(256), 0, stream,
                       qk, v, rot, out);
}